// Round 1
// 352.211 us; speedup vs baseline: 1.0017x; 1.0017x over previous
//
#include <hip/hip_runtime.h>
#include <math.h>

#define NNODES 50000
#define NEG_SLOPE 0.2f
#define NB 391       // ceil(50000/128) buckets
#define BW 128       // nodes per bucket
#define CHUNK 4096   // edges per block in bin_scatter
#define CAP 8128     // arena slots per bucket in tmp (mean 4224, sigma ~64)

typedef __bf16 bf16x8 __attribute__((ext_vector_type(8)));
typedef float f32x4 __attribute__((ext_vector_type(4)));

__device__ inline float rlane(float v, int l) {
    return __uint_as_float(__builtin_amdgcn_readlane((int)__float_as_uint(v), l));
}

// ---------------------------------------------------------------------------
// prep: W1 f32 -> bf16 panels [k/8][n][k%8]  +  bcur arena-cursor init.
// ---------------------------------------------------------------------------
__global__ void prep(const float* __restrict__ W1, __bf16* __restrict__ W1b,
                     int* __restrict__ bcur) {
    int i = blockIdx.x * 256 + threadIdx.x;
    if (i < NB) bcur[i] = i * CAP;
    else if (i == NB) bcur[NB] = 0;  // gcur (slot compaction cursor)
    if (i >= 512 * 64) return;
    int k = i >> 6, n = i & 63;
    W1b[((size_t)(k >> 3) * 64 + n) * 8 + (k & 7)] = (__bf16)W1[i];
}

// ---------------------------------------------------------------------------
// bin_scatter: per-block LDS bucket histogram -> one reservation atomic per
// bucket -> packed (dst&127)<<16|src into block-private contiguous tmp runs.
// ---------------------------------------------------------------------------
__global__ __launch_bounds__(256) void bin_scatter(const int* __restrict__ ei,
                                                   int E, int N, int* bcur,
                                                   int* __restrict__ tmp) {
    __shared__ int lcnt[NB];
    __shared__ int lbase[NB];
    int tid = threadIdx.x;
    int base0 = blockIdx.x * CHUNK;
    int lim = min(base0 + CHUNK, E + N);
    for (int i = tid; i < NB; i += 256) lcnt[i] = 0;
    __syncthreads();
    for (int e = base0 + tid; e < lim; e += 256) {
        int d = (e < E) ? ei[E + e] : e - E;  // row 1 = dst; tail = self-loops
        atomicAdd(&lcnt[d >> 7], 1);
    }
    __syncthreads();
    for (int b = tid; b < NB; b += 256) {
        int c = lcnt[b];
        lbase[b] = c ? atomicAdd(&bcur[b], c) : 0;
    }
    __syncthreads();
    for (int i = tid; i < NB; i += 256) lcnt[i] = 0;
    __syncthreads();
    for (int e = base0 + tid; e < lim; e += 256) {
        int s, d;
        if (e < E) { s = ei[e]; d = ei[E + e]; }
        else       { s = d = e - E; }
        int b = d >> 7;
        int p = atomicAdd(&lcnt[b], 1);
        tmp[lbase[b] + p] = ((d & 127) << 16) | s;  // src < 50000 < 2^16
    }
}

// ---------------------------------------------------------------------------
// csr_finalize: one block per bucket; per-node LDS count + scan; block
// reserves m compact slots from gcur; writes off/off_end and scatters slot.
// ---------------------------------------------------------------------------
__global__ __launch_bounds__(256) void csr_finalize(int* __restrict__ bcur,
                                                    const int* __restrict__ tmp,
                                                    int N, int* __restrict__ off,
                                                    int* __restrict__ off_end,
                                                    int* __restrict__ slot) {
    __shared__ int cnt[BW];
    __shared__ int cur[BW];
    __shared__ int cbase_s;
    int b = blockIdx.x, tid = threadIdx.x;
    int base = b * CAP;
    int m = bcur[b] - base;
    if (tid < BW) cnt[tid] = 0;
    __syncthreads();
    for (int i = tid; i < m; i += 256)
        atomicAdd(&cnt[(tmp[base + i] >> 16) & 127], 1);
    __syncthreads();
    if (tid == 0) cbase_s = atomicAdd(&bcur[NB], m);  // compact reservation
    int myv = (tid < BW) ? cnt[tid] : 0;
    for (int o = 1; o < BW; o <<= 1) {
        int u = 0;
        if (tid >= o && tid < BW) u = cnt[tid - o];
        __syncthreads();
        if (tid < BW) cnt[tid] += u;
        __syncthreads();
    }
    if (tid < BW) {
        int ex = cbase_s + cnt[tid] - myv;  // exclusive, compact coords
        cur[tid] = ex;
        int g = b * BW + tid;
        if (g < N) { off[g] = ex; off_end[g] = ex + myv; }
    }
    __syncthreads();
    for (int i = tid; i < m; i += 256) {
        int v = tmp[base + i];
        int k = (v >> 16) & 127;
        int p = atomicAdd(&cur[k], 1);
        slot[p] = v & 0xFFFF;
    }
}

// ---------------------------------------------------------------------------
// gemm1_mfma + fused att1: H1b[M,64](bf16) = bf16(X) @ bf16(W1); epilogue
// also computes a_src1[n,h], a_dst1[n,h] from the f32 accumulators.
// D-fragment: col = 16t + l15, row = quad*4 + r. h = 2t + (l15>>3).
// ---------------------------------------------------------------------------
__global__ __launch_bounds__(256) void gemm1_mfma(const float* __restrict__ X,
                                                  const __bf16* __restrict__ W1b,
                                                  const float* __restrict__ att_s1,
                                                  const float* __restrict__ att_d1,
                                                  __bf16* __restrict__ H1b,
                                                  float* __restrict__ a_s1,
                                                  float* __restrict__ a_d1,
                                                  int M) {
    __shared__ __bf16 As[2048];  // [kq 0..3][m 0..63][8]
    __shared__ __bf16 Bs[2048];  // [kq 0..3][n 0..63][8]
    int tid = threadIdx.x, wid = tid >> 6, lane = tid & 63;
    int quad = lane >> 4, l15 = lane & 15;
    int m0 = blockIdx.x * 64;
    f32x4 acc[4] = {{0.f, 0.f, 0.f, 0.f}, {0.f, 0.f, 0.f, 0.f},
                    {0.f, 0.f, 0.f, 0.f}, {0.f, 0.f, 0.f, 0.f}};
    int mrow = tid >> 2;   // 0..63 (staging role)
    int kq_w = tid & 3;    // k-chunk (staging role)
    int xrow = min(m0 + mrow, M - 1);  // clamp: garbage rows never stored
    const float* xp = X + (size_t)xrow * 512 + kq_w * 8;
    for (int kb = 0; kb < 16; ++kb) {
        float4 xa = *(const float4*)(xp + kb * 32);
        float4 xb = *(const float4*)(xp + kb * 32 + 4);
        bf16x8 av;
        av[0] = (__bf16)xa.x; av[1] = (__bf16)xa.y;
        av[2] = (__bf16)xa.z; av[3] = (__bf16)xa.w;
        av[4] = (__bf16)xb.x; av[5] = (__bf16)xb.y;
        av[6] = (__bf16)xb.z; av[7] = (__bf16)xb.w;
        *(bf16x8*)(As + ((size_t)kq_w * 64 + mrow) * 8) = av;
        *(bf16x8*)(Bs + ((size_t)wid * 64 + lane) * 8) =
            *(const bf16x8*)(W1b + ((size_t)(kb * 4 + wid) * 64 + lane) * 8);
        __syncthreads();
        bf16x8 af = *(const bf16x8*)(As + ((size_t)quad * 64 + 16 * wid + l15) * 8);
#pragma unroll
        for (int t = 0; t < 4; ++t) {
            bf16x8 bf = *(const bf16x8*)(Bs + ((size_t)quad * 64 + 16 * t + l15) * 8);
            acc[t] = __builtin_amdgcn_mfma_f32_16x16x32_bf16(af, bf, acc[t], 0, 0, 0);
        }
        __syncthreads();
    }
    float asv[4], adv[4];
#pragma unroll
    for (int t = 0; t < 4; ++t) {
        asv[t] = att_s1[16 * t + l15];
        adv[t] = att_d1[16 * t + l15];
    }
#pragma unroll
    for (int t = 0; t < 4; ++t) {
#pragma unroll
        for (int r = 0; r < 4; ++r) {
            int gm = m0 + 16 * wid + quad * 4 + r;
            if (gm < M) H1b[(size_t)gm * 64 + 16 * t + l15] = (__bf16)acc[t][r];
            float ps = acc[t][r] * asv[t];
            float pd = acc[t][r] * adv[t];
            ps += __shfl_xor(ps, 1); ps += __shfl_xor(ps, 2); ps += __shfl_xor(ps, 4);
            pd += __shfl_xor(pd, 1); pd += __shfl_xor(pd, 2); pd += __shfl_xor(pd, 4);
            if (gm < M && (l15 & 7) == 0) {
                int hh = 2 * t + (l15 >> 3);
                a_s1[(size_t)gm * 8 + hh] = ps;
                a_d1[(size_t)gm * 8 + hh] = pd;
            }
        }
    }
}

// ---------------------------------------------------------------------------
// agg1_fused (v2): wave per dst node. Lane roles transposed so NO cross-lane
// traffic in the edge loop: es = lane>>3 picks one of 8 edges/group, eh =
// lane&7 is BOTH the attention head and the 8-feature slice of that head
// (H1b row layout f = h*8+c). One bf16x8 load per lane covers all 8 rows of
// the group; w is lane-local (no bpermute/readlane); acc[8] = 8 independent
// FMA chains. Cross-edge reduction (shfl_xor over es bits) runs once/node.
// Epilogue: layer-2 GEMM via compile-time readlane of the replicated row
// (rows[] LDS round-trip deleted); H2b written PADDED to 64 cols for agg2.
// ---------------------------------------------------------------------------
__global__ __launch_bounds__(256) void agg1_fused(const int* __restrict__ off,
                                                  const int* __restrict__ off_end,
                                                  const int* __restrict__ slot,
                                                  const __bf16* __restrict__ H1b,
                                                  const float* __restrict__ a_src,
                                                  const float* __restrict__ a_dst,
                                                  const float* __restrict__ b1,
                                                  const float* __restrict__ W2,
                                                  const float* __restrict__ att_src2,
                                                  const float* __restrict__ att_dst2,
                                                  __bf16* __restrict__ H2b,
                                                  float* __restrict__ a_s2,
                                                  float* __restrict__ a_d2) {
    __shared__ float W2s[64 * 40];  // 10KB
    int tid = threadIdx.x;
    int wid = tid >> 6, lane = tid & 63;
    for (int i = tid; i < 64 * 40; i += 256) W2s[i] = W2[i];
    __syncthreads();  // W2s visible before any wave reaches the epilogue
    int d = blockIdx.x * 4 + wid;  // grid exact: 12500*4 = 50000
    int beg = off[d], end = off_end[d];
    int es = lane >> 3;  // edge sub-index within the 8-edge group
    int eh = lane & 7;   // head == feature slice (f = eh*8 + q)
    float adst_c = a_dst[(size_t)d * 8 + eh];
    const __bf16* hbase = H1b + eh * 8;
    float acc[8] = {0.f, 0.f, 0.f, 0.f, 0.f, 0.f, 0.f, 0.f};
    float den_l = 0.f;
#pragma unroll 2
    for (int i = beg; i < end; i += 8) {
        int j = i + es;
        int jj = (j < end) ? j : (end - 1);
        int s = slot[jj];
        float e = a_src[(size_t)s * 8 + eh] + adst_c;
        e = (e >= 0.f) ? e : NEG_SLOPE * e;
        float w = (j < end) ? __expf(e) : 0.f;
        den_l += w;
        bf16x8 hv = *(const bf16x8*)(hbase + (size_t)s * 64);
#pragma unroll
        for (int q = 0; q < 8; ++q) acc[q] += w * (float)hv[q];
    }
    // reduce over the 8 es-lanes (lane bits 3..5); all lanes end up replicated
#pragma unroll
    for (int m = 8; m <= 32; m <<= 1) {
        den_l += __shfl_xor(den_l, m);
#pragma unroll
        for (int q = 0; q < 8; ++q) acc[q] += __shfl_xor(acc[q], m);
    }
    float rden = 1.f / (den_l + 1e-16f);
    float vr[8];
#pragma unroll
    for (int q = 0; q < 8; ++q) {
        float t = acc[q] * rden + b1[eh * 8 + q];
        vr[q] = (t > 0.f) ? t : 0.f;  // relu'd H1R row, feature eh*8+q
    }
    // ---- fused layer-2 GEMM + att2: rp[k] via readlane (k compile-time) ----
    int c = lane, cc = (c < 40) ? c : 0;
    float acc2a = 0.f, acc2b = 0.f;
#pragma unroll
    for (int k = 0; k < 64; k += 2) {
        float r0 = rlane(vr[k & 7], k >> 3);
        float r1 = rlane(vr[(k + 1) & 7], (k + 1) >> 3);
        acc2a += r0 * W2s[k * 40 + cc];
        acc2b += r1 * W2s[(k + 1) * 40 + cc];
    }
    float acc2 = acc2a + acc2b;
    H2b[(size_t)d * 64 + c] = (__bf16)((c < 40) ? acc2 : 0.f);  // padded row
    float ps = (c < 40) ? acc2 * att_src2[cc] : 0.f;
    float pd = (c < 40) ? acc2 * att_dst2[cc] : 0.f;
#pragma unroll
    for (int mm = 32; mm >= 1; mm >>= 1) {
        ps += __shfl_xor(ps, mm);
        pd += __shfl_xor(pd, mm);
    }
    if (lane == 0) { a_s2[d] = ps; a_d2[d] = pd; }
}

// ---------------------------------------------------------------------------
// agg2 (v2): same transposed-lane structure as agg1_fused. H2b rows padded to
// 64 bf16 so lane (es=lane>>3, sl=lane&7) loads bf16x8 of edge es, channels
// sl*8..+7 (valid < 40). w is recomputed per-lane (broadcast loads). Entirely
// in-register log-softmax: channel reduce over sl bits (shfl_xor 1/2/4),
// lanes es==0 && sl<5 vector-store the 40 outputs. Zero LDS.
// ---------------------------------------------------------------------------
__global__ __launch_bounds__(256) void agg2(const int* __restrict__ off,
                                            const int* __restrict__ off_end,
                                            const int* __restrict__ slot,
                                            const __bf16* __restrict__ H2b,
                                            const float* __restrict__ a_src2,
                                            const float* __restrict__ a_d2,
                                            const float* __restrict__ b2,
                                            float* __restrict__ out) {
    int tid = threadIdx.x;
    int wid = tid >> 6, lane = tid & 63;
    int d = blockIdx.x * 4 + wid;  // grid exact
    int beg = off[d], end = off_end[d];
    int es = lane >> 3;  // edge sub-index
    int sl = lane & 7;   // channel slice (f = sl*8 + q, valid f < 40)
    float adst = a_d2[d];
    const __bf16* hbase = H2b + sl * 8;
    bool valid = (sl < 5);
    float acc[8] = {0.f, 0.f, 0.f, 0.f, 0.f, 0.f, 0.f, 0.f};
    float den_l = 0.f;
#pragma unroll 2
    for (int i = beg; i < end; i += 8) {
        int j = i + es;
        int jj = (j < end) ? j : (end - 1);
        int s = slot[jj];
        float e = a_src2[s] + adst;
        e = (e >= 0.f) ? e : NEG_SLOPE * e;
        float w = (j < end) ? __expf(e) : 0.f;
        den_l += w;
        bf16x8 hv = *(const bf16x8*)(hbase + (size_t)s * 64);
#pragma unroll
        for (int q = 0; q < 8; ++q) acc[q] += w * (float)hv[q];
    }
    // reduce over es-lanes (bits 3..5); w was replicated across sl, so this
    // sums each edge exactly once per (sl) lane
#pragma unroll
    for (int m = 8; m <= 32; m <<= 1) {
        den_l += __shfl_xor(den_l, m);
#pragma unroll
        for (int q = 0; q < 8; ++q) acc[q] += __shfl_xor(acc[q], m);
    }
    float rden = 1.f / (den_l + 1e-16f);
    float v[8];
    float vm = -3.0e38f;
#pragma unroll
    for (int q = 0; q < 8; ++q) {
        v[q] = acc[q] * rden + b2[valid ? sl * 8 + q : 0];
        vm = fmaxf(vm, v[q]);
    }
    if (!valid) vm = -3.0e38f;
    // channel max over the 5 valid slices: reduce over sl bits (0..2)
#pragma unroll
    for (int m = 1; m <= 4; m <<= 1) vm = fmaxf(vm, __shfl_xor(vm, m));
    float se = 0.f;
#pragma unroll
    for (int q = 0; q < 8; ++q) se += __expf(v[q] - vm);
    if (!valid) se = 0.f;
#pragma unroll
    for (int m = 1; m <= 4; m <<= 1) se += __shfl_xor(se, m);
    float lse = vm + __logf(se);
    if (es == 0 && valid) {
        f32x4 o0 = {v[0] - lse, v[1] - lse, v[2] - lse, v[3] - lse};
        f32x4 o1 = {v[4] - lse, v[5] - lse, v[6] - lse, v[7] - lse};
        *(f32x4*)(out + (size_t)d * 40 + sl * 8) = o0;
        *(f32x4*)(out + (size_t)d * 40 + sl * 8 + 4) = o1;
    }
}

// ---------------------------------------------------------------------------
extern "C" void kernel_launch(void* const* d_in, const int* in_sizes, int n_in,
                              void* d_out, int out_size, void* d_ws, size_t ws_size,
                              hipStream_t stream) {
    const float* x   = (const float*)d_in[0];
    const int*   ei  = (const int*)d_in[1];
    const float* W1  = (const float*)d_in[2];
    const float* as1 = (const float*)d_in[3];
    const float* ad1 = (const float*)d_in[4];
    const float* b1  = (const float*)d_in[5];
    const float* W2  = (const float*)d_in[6];
    const float* as2 = (const float*)d_in[7];
    const float* ad2 = (const float*)d_in[8];
    const float* b2  = (const float*)d_in[9];
    float* out = (float*)d_out;

    const int N = NNODES;
    const int E = in_sizes[1] / 2;
    const int total = E + N;

    // workspace carve-up
    char* ws = (char*)d_ws;
    size_t o = 0;
    auto alloc = [&](size_t bytes) -> void* {
        void* p = ws + o;
        o = (o + bytes + 255) & ~(size_t)255;
        return p;
    };
    int* bcur    = (int*)alloc((size_t)(NB + 1) * 4);  // +1: gcur at [NB]
    int* off     = (int*)alloc((size_t)N * 4);
    int* off_end = (int*)alloc((size_t)N * 4);
    int* slot    = (int*)alloc((size_t)total * 4);
    int* tmp     = (int*)alloc((size_t)NB * CAP * 4);  // 12.7MB bucket arena
    __bf16* W1b = (__bf16*)alloc((size_t)512 * 64 * 2);
    __bf16* H1b = (__bf16*)alloc((size_t)N * 64 * 2);
    float* a_s1 = (float*)alloc((size_t)N * 8 * 4);
    float* a_d1 = (float*)alloc((size_t)N * 8 * 4);
    __bf16* H2b = (__bf16*)alloc((size_t)N * 64 * 2);  // PADDED to 64 cols
    float* a_s2 = (float*)alloc((size_t)N * 4);
    float* a_d2 = (float*)alloc((size_t)N * 4);
    (void)ws_size; (void)n_in; (void)out_size;

    // prep (W1 pack + bcur init), then binned CSR build (shared by layers)
    prep<<<(512 * 64 + 255) / 256, 256, 0, stream>>>(W1, W1b, bcur);
    bin_scatter<<<(total + CHUNK - 1) / CHUNK, 256, 0, stream>>>(ei, E, N, bcur, tmp);
    csr_finalize<<<NB, 256, 0, stream>>>(bcur, tmp, N, off, off_end, slot);

    // Layer 1 GEMM (+att1 fused)
    gemm1_mfma<<<(N + 63) / 64, 256, 0, stream>>>(x, W1b, as1, ad1, H1b, a_s1, a_d1, N);

    // Layer-1 aggregation + fused layer-2 GEMM/att2
    agg1_fused<<<N / 4, 256, 0, stream>>>(off, off_end, slot, H1b, a_s1, a_d1, b1,
                                          W2, as2, ad2, H2b, a_s2, a_d2);

    // Layer-2 aggregation + bias + log_softmax
    agg2<<<N / 4, 256, 0, stream>>>(off, off_end, slot, H2b, a_s2, a_d2, b2, out);
}

// Round 2
// 343.541 us; speedup vs baseline: 1.0269x; 1.0252x over previous
//
#include <hip/hip_runtime.h>
#include <math.h>

#define NNODES 50000
#define NEG_SLOPE 0.2f
#define NB 391       // ceil(50000/128) buckets
#define BW 128       // nodes per bucket
#define CHUNK 4096   // edges per block in bin_scatter
#define CAP 8128     // arena slots per bucket in tmp (mean 4224, sigma ~64)

typedef __bf16 bf16x8 __attribute__((ext_vector_type(8)));
typedef float f32x4 __attribute__((ext_vector_type(4)));

__device__ inline float rlane(float v, int l) {
    return __uint_as_float(__builtin_amdgcn_readlane((int)__float_as_uint(v), l));
}

// ---------------------------------------------------------------------------
// prep: W1 f32 -> bf16 panels [k/8][n][k%8]  +  bcur arena-cursor init.
// ---------------------------------------------------------------------------
__global__ void prep(const float* __restrict__ W1, __bf16* __restrict__ W1b,
                     int* __restrict__ bcur) {
    int i = blockIdx.x * 256 + threadIdx.x;
    if (i < NB) bcur[i] = i * CAP;
    else if (i == NB) bcur[NB] = 0;  // gcur (slot compaction cursor)
    if (i >= 512 * 64) return;
    int k = i >> 6, n = i & 63;
    W1b[((size_t)(k >> 3) * 64 + n) * 8 + (k & 7)] = (__bf16)W1[i];
}

// ---------------------------------------------------------------------------
// bin_scatter: per-block LDS bucket histogram -> one reservation atomic per
// bucket -> packed (dst&127)<<16|src into block-private contiguous tmp runs.
// ---------------------------------------------------------------------------
__global__ __launch_bounds__(256) void bin_scatter(const int* __restrict__ ei,
                                                   int E, int N, int* bcur,
                                                   int* __restrict__ tmp) {
    __shared__ int lcnt[NB];
    __shared__ int lbase[NB];
    int tid = threadIdx.x;
    int base0 = blockIdx.x * CHUNK;
    int lim = min(base0 + CHUNK, E + N);
    for (int i = tid; i < NB; i += 256) lcnt[i] = 0;
    __syncthreads();
    for (int e = base0 + tid; e < lim; e += 256) {
        int d = (e < E) ? ei[E + e] : e - E;  // row 1 = dst; tail = self-loops
        atomicAdd(&lcnt[d >> 7], 1);
    }
    __syncthreads();
    for (int b = tid; b < NB; b += 256) {
        int c = lcnt[b];
        lbase[b] = c ? atomicAdd(&bcur[b], c) : 0;
    }
    __syncthreads();
    for (int i = tid; i < NB; i += 256) lcnt[i] = 0;
    __syncthreads();
    for (int e = base0 + tid; e < lim; e += 256) {
        int s, d;
        if (e < E) { s = ei[e]; d = ei[E + e]; }
        else       { s = d = e - E; }
        int b = d >> 7;
        int p = atomicAdd(&lcnt[b], 1);
        tmp[lbase[b] + p] = ((d & 127) << 16) | s;  // src < 50000 < 2^16
    }
}

// ---------------------------------------------------------------------------
// csr_finalize: one block per bucket; per-node LDS count + scan; block
// reserves m compact slots from gcur; writes off/off_end and scatters slot.
// ---------------------------------------------------------------------------
__global__ __launch_bounds__(256) void csr_finalize(int* __restrict__ bcur,
                                                    const int* __restrict__ tmp,
                                                    int N, int* __restrict__ off,
                                                    int* __restrict__ off_end,
                                                    int* __restrict__ slot) {
    __shared__ int cnt[BW];
    __shared__ int cur[BW];
    __shared__ int cbase_s;
    int b = blockIdx.x, tid = threadIdx.x;
    int base = b * CAP;
    int m = bcur[b] - base;
    if (tid < BW) cnt[tid] = 0;
    __syncthreads();
    for (int i = tid; i < m; i += 256)
        atomicAdd(&cnt[(tmp[base + i] >> 16) & 127], 1);
    __syncthreads();
    if (tid == 0) cbase_s = atomicAdd(&bcur[NB], m);  // compact reservation
    int myv = (tid < BW) ? cnt[tid] : 0;
    for (int o = 1; o < BW; o <<= 1) {
        int u = 0;
        if (tid >= o && tid < BW) u = cnt[tid - o];
        __syncthreads();
        if (tid < BW) cnt[tid] += u;
        __syncthreads();
    }
    if (tid < BW) {
        int ex = cbase_s + cnt[tid] - myv;  // exclusive, compact coords
        cur[tid] = ex;
        int g = b * BW + tid;
        if (g < N) { off[g] = ex; off_end[g] = ex + myv; }
    }
    __syncthreads();
    for (int i = tid; i < m; i += 256) {
        int v = tmp[base + i];
        int k = (v >> 16) & 127;
        int p = atomicAdd(&cur[k], 1);
        slot[p] = v & 0xFFFF;
    }
}

// ---------------------------------------------------------------------------
// gemm1_mfma + fused att1: H1b[M,64](bf16) = bf16(X) @ bf16(W1); epilogue
// also computes a_src1[n,h], a_dst1[n,h] from the f32 accumulators.
// D-fragment: col = 16t + l15, row = quad*4 + r. h = 2t + (l15>>3).
// ---------------------------------------------------------------------------
__global__ __launch_bounds__(256) void gemm1_mfma(const float* __restrict__ X,
                                                  const __bf16* __restrict__ W1b,
                                                  const float* __restrict__ att_s1,
                                                  const float* __restrict__ att_d1,
                                                  __bf16* __restrict__ H1b,
                                                  float* __restrict__ a_s1,
                                                  float* __restrict__ a_d1,
                                                  int M) {
    __shared__ __bf16 As[2048];  // [kq 0..3][m 0..63][8]
    __shared__ __bf16 Bs[2048];  // [kq 0..3][n 0..63][8]
    int tid = threadIdx.x, wid = tid >> 6, lane = tid & 63;
    int quad = lane >> 4, l15 = lane & 15;
    int m0 = blockIdx.x * 64;
    f32x4 acc[4] = {{0.f, 0.f, 0.f, 0.f}, {0.f, 0.f, 0.f, 0.f},
                    {0.f, 0.f, 0.f, 0.f}, {0.f, 0.f, 0.f, 0.f}};
    int mrow = tid >> 2;   // 0..63 (staging role)
    int kq_w = tid & 3;    // k-chunk (staging role)
    int xrow = min(m0 + mrow, M - 1);  // clamp: garbage rows never stored
    const float* xp = X + (size_t)xrow * 512 + kq_w * 8;
    for (int kb = 0; kb < 16; ++kb) {
        float4 xa = *(const float4*)(xp + kb * 32);
        float4 xb = *(const float4*)(xp + kb * 32 + 4);
        bf16x8 av;
        av[0] = (__bf16)xa.x; av[1] = (__bf16)xa.y;
        av[2] = (__bf16)xa.z; av[3] = (__bf16)xa.w;
        av[4] = (__bf16)xb.x; av[5] = (__bf16)xb.y;
        av[6] = (__bf16)xb.z; av[7] = (__bf16)xb.w;
        *(bf16x8*)(As + ((size_t)kq_w * 64 + mrow) * 8) = av;
        *(bf16x8*)(Bs + ((size_t)wid * 64 + lane) * 8) =
            *(const bf16x8*)(W1b + ((size_t)(kb * 4 + wid) * 64 + lane) * 8);
        __syncthreads();
        bf16x8 af = *(const bf16x8*)(As + ((size_t)quad * 64 + 16 * wid + l15) * 8);
#pragma unroll
        for (int t = 0; t < 4; ++t) {
            bf16x8 bf = *(const bf16x8*)(Bs + ((size_t)quad * 64 + 16 * t + l15) * 8);
            acc[t] = __builtin_amdgcn_mfma_f32_16x16x32_bf16(af, bf, acc[t], 0, 0, 0);
        }
        __syncthreads();
    }
    float asv[4], adv[4];
#pragma unroll
    for (int t = 0; t < 4; ++t) {
        asv[t] = att_s1[16 * t + l15];
        adv[t] = att_d1[16 * t + l15];
    }
#pragma unroll
    for (int t = 0; t < 4; ++t) {
#pragma unroll
        for (int r = 0; r < 4; ++r) {
            int gm = m0 + 16 * wid + quad * 4 + r;
            if (gm < M) H1b[(size_t)gm * 64 + 16 * t + l15] = (__bf16)acc[t][r];
            float ps = acc[t][r] * asv[t];
            float pd = acc[t][r] * adv[t];
            ps += __shfl_xor(ps, 1); ps += __shfl_xor(ps, 2); ps += __shfl_xor(ps, 4);
            pd += __shfl_xor(pd, 1); pd += __shfl_xor(pd, 2); pd += __shfl_xor(pd, 4);
            if (gm < M && (l15 & 7) == 0) {
                int hh = 2 * t + (l15 >> 3);
                a_s1[(size_t)gm * 8 + hh] = ps;
                a_d1[(size_t)gm * 8 + hh] = pd;
            }
        }
    }
}

// one edge group at compile-time-known batch position; masked when idx >= deg
#define EDGE_GROUP1(IDX, SVAR, WVAR, HVAR, EVAR)                        \
    int SVAR = __shfl(sv, ((IDX) < deg) ? (IDX) : dm1);                 \
    float EVAR = a_src[(size_t)SVAR * 8 + eh] + adst_c;                 \
    EVAR = (EVAR >= 0.f) ? EVAR : NEG_SLOPE * EVAR;                     \
    float WVAR = ((IDX) < deg) ? __expf(EVAR) : 0.f;                    \
    bf16x8 HVAR = *(const bf16x8*)(hbase + (size_t)SVAR * 64);

// ---------------------------------------------------------------------------
// agg1_fused (v3): wave per dst node, transposed lane roles (es=lane>>3 edge,
// eh=lane&7 head/feature-slice).  NEW: the whole adjacency list is fetched
// with ONE coalesced 64-wide slot load (degree <= 64 for ~all nodes;
// exact fallback loop for the tail), s distributed via ds_bpermute, and the
// a_src/H1b gathers for 4 groups are issued in a single burst -> the serial
// L2/L3 round-trip chain per node collapses from ~8 rounds to ~2.
// W2s barrier moved AFTER the edge loop (no block-startup serialization).
// ---------------------------------------------------------------------------
__global__ __launch_bounds__(256, 8) void agg1_fused(const int* __restrict__ off,
                                                  const int* __restrict__ off_end,
                                                  const int* __restrict__ slot,
                                                  const __bf16* __restrict__ H1b,
                                                  const float* __restrict__ a_src,
                                                  const float* __restrict__ a_dst,
                                                  const float* __restrict__ b1,
                                                  const float* __restrict__ W2,
                                                  const float* __restrict__ att_src2,
                                                  const float* __restrict__ att_dst2,
                                                  __bf16* __restrict__ H2b,
                                                  float* __restrict__ a_s2,
                                                  float* __restrict__ a_d2) {
    __shared__ float W2s[64 * 40];  // 10KB
    int tid = threadIdx.x;
    int wid = tid >> 6, lane = tid & 63;
    for (int i = tid; i < 64 * 40; i += 256) W2s[i] = W2[i];
    // NOTE: __syncthreads() deferred to just before the epilogue (W2s use)
    int d = blockIdx.x * 4 + wid;  // grid exact: 12500*4 = 50000
    int beg = off[d], end = off_end[d];
    int deg = end - beg, dm1 = deg - 1;
    int es = lane >> 3;  // edge sub-index within the 8-edge group
    int eh = lane & 7;   // head == feature slice (f = eh*8 + q)
    float adst_c = a_dst[(size_t)d * 8 + eh];
    const __bf16* hbase = H1b + eh * 8;
    // one coalesced load grabs the whole adjacency list (deg<=64 common case)
    int sv = slot[beg + ((lane < deg) ? lane : dm1)];
    float acc[8] = {0.f, 0.f, 0.f, 0.f, 0.f, 0.f, 0.f, 0.f};
    float den_l = 0.f;
    {   // prologue: groups 0..3 (idx 0..31) in one burst, masked by deg
        EDGE_GROUP1(es,      s0, w0, h0, e0)
        EDGE_GROUP1(8 + es,  s1, w1, h1, e1)
        EDGE_GROUP1(16 + es, s2, w2, h2, e2)
        EDGE_GROUP1(24 + es, s3, w3, h3, e3)
        den_l = ((w0 + w1) + (w2 + w3));
#pragma unroll
        for (int q = 0; q < 8; ++q)
            acc[q] = w0 * (float)h0[q] + w1 * (float)h1[q] +
                     w2 * (float)h2[q] + w3 * (float)h3[q];
    }
    int dcap = (deg < 64) ? deg : 64;
    for (int b = 32; b < dcap; b += 16) {  // groups 4..7, 2-wide
        EDGE_GROUP1(b + es,     s0, w0, h0, e0)
        EDGE_GROUP1(b + 8 + es, s1, w1, h1, e1)
        den_l += w0 + w1;
#pragma unroll
        for (int q = 0; q < 8; ++q)
            acc[q] += w0 * (float)h0[q] + w1 * (float)h1[q];
    }
    // exact tail for the (vanishingly rare) deg > 64 nodes
    for (int i = beg + 64; i < end; i += 8) {
        int j = i + es;
        int jj = (j < end) ? j : (end - 1);
        int s = slot[jj];
        float e = a_src[(size_t)s * 8 + eh] + adst_c;
        e = (e >= 0.f) ? e : NEG_SLOPE * e;
        float w = (j < end) ? __expf(e) : 0.f;
        den_l += w;
        bf16x8 hv = *(const bf16x8*)(hbase + (size_t)s * 64);
#pragma unroll
        for (int q = 0; q < 8; ++q) acc[q] += w * (float)hv[q];
    }
    // reduce over the 8 es-lanes (lane bits 3..5); all lanes end up replicated
#pragma unroll
    for (int m = 8; m <= 32; m <<= 1) {
        den_l += __shfl_xor(den_l, m);
#pragma unroll
        for (int q = 0; q < 8; ++q) acc[q] += __shfl_xor(acc[q], m);
    }
    float rden = 1.f / (den_l + 1e-16f);
    float vr[8];
#pragma unroll
    for (int q = 0; q < 8; ++q) {
        float t = acc[q] * rden + b1[eh * 8 + q];
        vr[q] = (t > 0.f) ? t : 0.f;  // relu'd H1R row, feature eh*8+q
    }
    __syncthreads();  // W2s visible (staged at block start, used below)
    // ---- fused layer-2 GEMM + att2: rp[k] via readlane (k compile-time) ----
    int c = lane, cc = (c < 40) ? c : 0;
    float acc2a = 0.f, acc2b = 0.f;
#pragma unroll
    for (int k = 0; k < 64; k += 2) {
        float r0 = rlane(vr[k & 7], k >> 3);
        float r1 = rlane(vr[(k + 1) & 7], (k + 1) >> 3);
        acc2a += r0 * W2s[k * 40 + cc];
        acc2b += r1 * W2s[(k + 1) * 40 + cc];
    }
    float acc2 = acc2a + acc2b;
    H2b[(size_t)d * 64 + c] = (__bf16)((c < 40) ? acc2 : 0.f);  // padded row
    float ps = (c < 40) ? acc2 * att_src2[cc] : 0.f;
    float pd = (c < 40) ? acc2 * att_dst2[cc] : 0.f;
#pragma unroll
    for (int mm = 32; mm >= 1; mm >>= 1) {
        ps += __shfl_xor(ps, mm);
        pd += __shfl_xor(pd, mm);
    }
    if (lane == 0) { a_s2[d] = ps; a_d2[d] = pd; }
}

// one agg2 edge group; a_src2 is per-node scalar here
#define EDGE_GROUP2(IDX, SVAR, WVAR, HVAR, EVAR)                        \
    int SVAR = __shfl(sv, ((IDX) < deg) ? (IDX) : dm1);                 \
    float EVAR = a_src2[SVAR] + adst;                                   \
    EVAR = (EVAR >= 0.f) ? EVAR : NEG_SLOPE * EVAR;                     \
    float WVAR = ((IDX) < deg) ? __expf(EVAR) : 0.f;                    \
    bf16x8 HVAR = *(const bf16x8*)(hbase + (size_t)SVAR * 64);

// ---------------------------------------------------------------------------
// agg2 (v3): same burst-gather structure as agg1 v3.  H2b rows padded to 64
// bf16 (cols 40..63 are zeros).  In-register log-softmax, zero LDS.
// ---------------------------------------------------------------------------
__global__ __launch_bounds__(256, 8) void agg2(const int* __restrict__ off,
                                            const int* __restrict__ off_end,
                                            const int* __restrict__ slot,
                                            const __bf16* __restrict__ H2b,
                                            const float* __restrict__ a_src2,
                                            const float* __restrict__ a_d2,
                                            const float* __restrict__ b2,
                                            float* __restrict__ out) {
    int tid = threadIdx.x;
    int wid = tid >> 6, lane = tid & 63;
    int d = blockIdx.x * 4 + wid;  // grid exact
    int beg = off[d], end = off_end[d];
    int deg = end - beg, dm1 = deg - 1;
    int es = lane >> 3;  // edge sub-index
    int sl = lane & 7;   // channel slice (f = sl*8 + q, valid f < 40)
    float adst = a_d2[d];
    const __bf16* hbase = H2b + sl * 8;
    bool valid = (sl < 5);
    int sv = slot[beg + ((lane < deg) ? lane : dm1)];
    float acc[8] = {0.f, 0.f, 0.f, 0.f, 0.f, 0.f, 0.f, 0.f};
    float den_l = 0.f;
    {   // prologue burst: groups 0..3
        EDGE_GROUP2(es,      s0, w0, h0, e0)
        EDGE_GROUP2(8 + es,  s1, w1, h1, e1)
        EDGE_GROUP2(16 + es, s2, w2, h2, e2)
        EDGE_GROUP2(24 + es, s3, w3, h3, e3)
        den_l = ((w0 + w1) + (w2 + w3));
#pragma unroll
        for (int q = 0; q < 8; ++q)
            acc[q] = w0 * (float)h0[q] + w1 * (float)h1[q] +
                     w2 * (float)h2[q] + w3 * (float)h3[q];
    }
    int dcap = (deg < 64) ? deg : 64;
    for (int b = 32; b < dcap; b += 16) {
        EDGE_GROUP2(b + es,     s0, w0, h0, e0)
        EDGE_GROUP2(b + 8 + es, s1, w1, h1, e1)
        den_l += w0 + w1;
#pragma unroll
        for (int q = 0; q < 8; ++q)
            acc[q] += w0 * (float)h0[q] + w1 * (float)h1[q];
    }
    for (int i = beg + 64; i < end; i += 8) {  // rare deg>64 tail
        int j = i + es;
        int jj = (j < end) ? j : (end - 1);
        int s = slot[jj];
        float e = a_src2[s] + adst;
        e = (e >= 0.f) ? e : NEG_SLOPE * e;
        float w = (j < end) ? __expf(e) : 0.f;
        den_l += w;
        bf16x8 hv = *(const bf16x8*)(hbase + (size_t)s * 64);
#pragma unroll
        for (int q = 0; q < 8; ++q) acc[q] += w * (float)hv[q];
    }
    // reduce over es-lanes (bits 3..5); w was replicated across sl, so this
    // sums each edge exactly once per (sl) lane
#pragma unroll
    for (int m = 8; m <= 32; m <<= 1) {
        den_l += __shfl_xor(den_l, m);
#pragma unroll
        for (int q = 0; q < 8; ++q) acc[q] += __shfl_xor(acc[q], m);
    }
    float rden = 1.f / (den_l + 1e-16f);
    float v[8];
    float vm = -3.0e38f;
#pragma unroll
    for (int q = 0; q < 8; ++q) {
        v[q] = acc[q] * rden + b2[valid ? sl * 8 + q : 0];
        vm = fmaxf(vm, v[q]);
    }
    if (!valid) vm = -3.0e38f;
    // channel max over the 5 valid slices: reduce over sl bits (0..2)
#pragma unroll
    for (int m = 1; m <= 4; m <<= 1) vm = fmaxf(vm, __shfl_xor(vm, m));
    float se = 0.f;
#pragma unroll
    for (int q = 0; q < 8; ++q) se += __expf(v[q] - vm);
    if (!valid) se = 0.f;
#pragma unroll
    for (int m = 1; m <= 4; m <<= 1) se += __shfl_xor(se, m);
    float lse = vm + __logf(se);
    if (es == 0 && valid) {
        f32x4 o0 = {v[0] - lse, v[1] - lse, v[2] - lse, v[3] - lse};
        f32x4 o1 = {v[4] - lse, v[5] - lse, v[6] - lse, v[7] - lse};
        *(f32x4*)(out + (size_t)d * 40 + sl * 8) = o0;
        *(f32x4*)(out + (size_t)d * 40 + sl * 8 + 4) = o1;
    }
}

// ---------------------------------------------------------------------------
extern "C" void kernel_launch(void* const* d_in, const int* in_sizes, int n_in,
                              void* d_out, int out_size, void* d_ws, size_t ws_size,
                              hipStream_t stream) {
    const float* x   = (const float*)d_in[0];
    const int*   ei  = (const int*)d_in[1];
    const float* W1  = (const float*)d_in[2];
    const float* as1 = (const float*)d_in[3];
    const float* ad1 = (const float*)d_in[4];
    const float* b1  = (const float*)d_in[5];
    const float* W2  = (const float*)d_in[6];
    const float* as2 = (const float*)d_in[7];
    const float* ad2 = (const float*)d_in[8];
    const float* b2  = (const float*)d_in[9];
    float* out = (float*)d_out;

    const int N = NNODES;
    const int E = in_sizes[1] / 2;
    const int total = E + N;

    // workspace carve-up
    char* ws = (char*)d_ws;
    size_t o = 0;
    auto alloc = [&](size_t bytes) -> void* {
        void* p = ws + o;
        o = (o + bytes + 255) & ~(size_t)255;
        return p;
    };
    int* bcur    = (int*)alloc((size_t)(NB + 1) * 4);  // +1: gcur at [NB]
    int* off     = (int*)alloc((size_t)N * 4);
    int* off_end = (int*)alloc((size_t)N * 4);
    int* slot    = (int*)alloc((size_t)total * 4);
    int* tmp     = (int*)alloc((size_t)NB * CAP * 4);  // 12.7MB bucket arena
    __bf16* W1b = (__bf16*)alloc((size_t)512 * 64 * 2);
    __bf16* H1b = (__bf16*)alloc((size_t)N * 64 * 2);
    float* a_s1 = (float*)alloc((size_t)N * 8 * 4);
    float* a_d1 = (float*)alloc((size_t)N * 8 * 4);
    __bf16* H2b = (__bf16*)alloc((size_t)N * 64 * 2);  // PADDED to 64 cols
    float* a_s2 = (float*)alloc((size_t)N * 4);
    float* a_d2 = (float*)alloc((size_t)N * 4);
    (void)ws_size; (void)n_in; (void)out_size;

    // prep (W1 pack + bcur init), then binned CSR build (shared by layers)
    prep<<<(512 * 64 + 255) / 256, 256, 0, stream>>>(W1, W1b, bcur);
    bin_scatter<<<(total + CHUNK - 1) / CHUNK, 256, 0, stream>>>(ei, E, N, bcur, tmp);
    csr_finalize<<<NB, 256, 0, stream>>>(bcur, tmp, N, off, off_end, slot);

    // Layer 1 GEMM (+att1 fused)
    gemm1_mfma<<<(N + 63) / 64, 256, 0, stream>>>(x, W1b, as1, ad1, H1b, a_s1, a_d1, N);

    // Layer-1 aggregation + fused layer-2 GEMM/att2
    agg1_fused<<<N / 4, 256, 0, stream>>>(off, off_end, slot, H1b, a_s1, a_d1, b1,
                                          W2, as2, ad2, H2b, a_s2, a_d2);

    // Layer-2 aggregation + bias + log_softmax
    agg2<<<N / 4, 256, 0, stream>>>(off, off_end, slot, H2b, a_s2, a_d2, b2, out);
}